// Round 5
// baseline (795.661 us; speedup 1.0000x reference)
//
#include <hip/hip_runtime.h>

#define MDIM 4096
#define KDIM 4096
#define NDIM 11008
#define NGROUPS 32

#define BM 256
#define BN 256
#define BK 64
#define NT (KDIM / BK)   // 64 K-tiles
#define KB (KDIM * 2)    // row stride in bytes (8192)

typedef _Float16 f16x8 __attribute__((ext_vector_type(8)));
typedef float f32x4 __attribute__((ext_vector_type(4)));

typedef const unsigned int __attribute__((address_space(1))) *gas_t;
typedef unsigned int __attribute__((address_space(3))) *las_t;

__device__ __forceinline__ void gld_lds16(const void *g, void *l) {
  __builtin_amdgcn_global_load_lds((gas_t)g, (las_t)l, 16, 0, 0);
}

// Raw barrier with memory clobber (no implicit vm/lgkm drain).
#define BAR() asm volatile("s_barrier" ::: "memory")
#define VMW8() asm volatile("s_waitcnt vmcnt(8)" ::: "memory")
#define VMW0() asm volatile("s_waitcnt vmcnt(0)" ::: "memory")
#define FENCE() __builtin_amdgcn_sched_barrier(0)

// ---------------- prepass: A fp32 -> f16 ----------------
__global__ __launch_bounds__(256) void cvt_a_kernel(const float *__restrict__ a,
                                                    _Float16 *__restrict__ o) {
  const int n8 = (MDIM * KDIM) / 8;
  for (int i = blockIdx.x * blockDim.x + threadIdx.x; i < n8;
       i += gridDim.x * blockDim.x) {
    const float4 v0 = *(const float4 *)(a + (size_t)i * 8);
    const float4 v1 = *(const float4 *)(a + (size_t)i * 8 + 4);
    f16x8 h;
    h[0] = (_Float16)v0.x; h[1] = (_Float16)v0.y;
    h[2] = (_Float16)v0.z; h[3] = (_Float16)v0.w;
    h[4] = (_Float16)v1.x; h[5] = (_Float16)v1.y;
    h[6] = (_Float16)v1.z; h[7] = (_Float16)v1.w;
    *(f16x8 *)(o + (size_t)i * 8) = h;
  }
}

// ---------------- prepass: W int32 -> f16 * scale ----------------
__global__ __launch_bounds__(256) void cvt_w_kernel(const int *__restrict__ w,
                                                    const float *__restrict__ s,
                                                    _Float16 *__restrict__ o) {
  const int n8 = (NDIM * KDIM) / 8;
  for (int i = blockIdx.x * blockDim.x + threadIdx.x; i < n8;
       i += gridDim.x * blockDim.x) {
    const size_t base = (size_t)i * 8;
    const int row = (int)(base >> 12);             // /KDIM
    const int g = ((int)(base & (KDIM - 1))) >> 7; // /GROUPSIZE
    const float sc = s[row * NGROUPS + g];
    const int4 w0 = *(const int4 *)(w + base);
    const int4 w1 = *(const int4 *)(w + base + 4);
    f16x8 h;
    h[0] = (_Float16)((float)w0.x * sc); h[1] = (_Float16)((float)w0.y * sc);
    h[2] = (_Float16)((float)w0.z * sc); h[3] = (_Float16)((float)w0.w * sc);
    h[4] = (_Float16)((float)w1.x * sc); h[5] = (_Float16)((float)w1.y * sc);
    h[6] = (_Float16)((float)w1.z * sc); h[7] = (_Float16)((float)w1.w * sc);
    *(f16x8 *)(o + base) = h;
  }
}

// ---------------- main GEMM: 256x256 tile, BK=64, 8 waves ------------------
// ROTATING-QUADRANT schedule. Quadrant cycle c = [Q00,Q01,Q11,Q10]; tile t
// phase p runs quadrant c[(t+p)&3]. Consequence: every register group
// (af0,bf1,af1,bf0 = cycle-adjacent pairs) has its two uses in adjacent
// phases of the stream, exactly one group frees per phase, and the 24
// fragment reads/wave/tile spread 8,4,8,4 across phases (LDS pipe ~576
// cyc/CU/phase ~= MFMA 620) instead of R0's 16-read tail bunch.
// Per tile t (r=t&3, b=t&1, cur=buf b (tile-t data), nxt=buf b^1 (t+1 data)):
//   P1: read g[(r+1)&3] <- cur;           MFMA c[r]
//   P2: read g[(r+2)&3] <- cur;           MFMA c[r+1]; vmcnt(0); BAR
//   P3: read g[r]       <- nxt (t+1 copy) MFMA c[r+2]
//   P4: stage A/B(t+2)->buf b (8 glds);   MFMA c[r+3]; read g[(r+1)&3]<-nxt; BAR
// with g = [A0, B1, A1, B0]. All reads' operands are >=1 phase old except
// the alternating 4/8-read P4 tail (consumed next-P1). vmcnt(0) at P2
// retires stage loads issued at (t-1)-P4 (~3 phases old - never blocks).
// Staging into buf b at P4 is safely after cur-reads (P1/P2, drained by
// P2/P3 MFMA lgkm waits) and the mid-tile barrier.
// LDS XOR-swizzle (16B involution): phys_koff = koff ^ ((row&7)*16), applied
// to the pre-swizzled staging source AND the ds_read address.
__global__ __launch_bounds__(512, 2) void gemm_8phase(
    const _Float16 *__restrict__ Ah, const _Float16 *__restrict__ Wh,
    float *__restrict__ C) {
  __shared__ __align__(16) _Float16 As[2][BM * BK];
  __shared__ __align__(16) _Float16 Bs[2][BN * BK];

  const int tid = threadIdx.x;
  const int l = tid & 63;
  const int w = tid >> 6;   // wave 0..7
  const int wm = w >> 2;    // 0..1 (M half)
  const int wn = w & 3;     // 0..3 (N quarter)

  // XCD-aware bijective swizzle: 688 blocks, 86 per XCD.
  const int wg = blockIdx.x;
  const int swz = (wg & 7) * 86 + (wg >> 3);
  const int bx = swz / 16;   // N tile 0..42
  const int by = swz % 16;   // M tile 0..15

  // staging source (pre-swizzled per lane)
  const int srow = l >> 3;
  const int gk = ((l & 7) ^ srow) * 16;
  const char *Ag =
      (const char *)Ah + (size_t)(by * BM + w * 8 + srow) * KB + gk;
  const char *Bg =
      (const char *)Wh + (size_t)(bx * BN + w * 8 + srow) * KB + gk;

  // fragment-read offsets (bytes)
  const int laneRow = (l & 15) * (BK * 2);
  const int kx0 = ((l >> 4) * 16) ^ ((l & 7) * 16);
  const int kx1 = kx0 ^ 64;

  f32x4 acc[8][4] = {};
  f16x8 af0[4][2], af1[4][2], bf0[2][2], bf1[2][2];

#define STAGE2_A(KT, B, S0)                                                   \
  {                                                                           \
    const char *ap_ = Ag + (size_t)(KT) * (BK * 2);                           \
    gld_lds16(ap_ + (size_t)(S0) * (64 * KB),                                 \
              (void *)&As[B][(S0) * 4096 + w * 512]);                         \
    gld_lds16(ap_ + (size_t)((S0) + 1) * (64 * KB),                           \
              (void *)&As[B][((S0) + 1) * 4096 + w * 512]);                   \
  }

#define STAGE2_B(KT, B, S0)                                                   \
  {                                                                           \
    const char *bp_ = Bg + (size_t)(KT) * (BK * 2);                           \
    gld_lds16(bp_ + (size_t)(S0) * (64 * KB),                                 \
              (void *)&Bs[B][(S0) * 4096 + w * 512]);                         \
    gld_lds16(bp_ + (size_t)((S0) + 1) * (64 * KB),                           \
              (void *)&Bs[B][((S0) + 1) * 4096 + w * 512]);                   \
  }

#define LDA_Q(DST, QM, BASE)                                                  \
  {                                                                           \
    const char *ba_ = (BASE) + (wm * 128 + (QM) * 64) * (BK * 2) + laneRow;   \
    _Pragma("unroll") for (int mi = 0; mi < 4; ++mi) {                        \
      DST[mi][0] = *(const f16x8 *)(ba_ + mi * 2048 + kx0);                   \
      DST[mi][1] = *(const f16x8 *)(ba_ + mi * 2048 + kx1);                   \
    }                                                                         \
  }

#define LDB_Q(DST, QN, BASE)                                                  \
  {                                                                           \
    const char *bb_ = (BASE) + (wn * 64 + (QN) * 32) * (BK * 2) + laneRow;    \
    _Pragma("unroll") for (int nj = 0; nj < 2; ++nj) {                        \
      DST[nj][0] = *(const f16x8 *)(bb_ + nj * 2048 + kx0);                   \
      DST[nj][1] = *(const f16x8 *)(bb_ + nj * 2048 + kx1);                   \
    }                                                                         \
  }

#define MMA_Q(AF, BF, QM, QN)                                                 \
  __builtin_amdgcn_s_setprio(1);                                              \
  _Pragma("unroll") for (int ks = 0; ks < 2; ++ks)                            \
      _Pragma("unroll") for (int mi = 0; mi < 4; ++mi)                        \
          _Pragma("unroll") for (int nj = 0; nj < 2; ++nj)                    \
              acc[(QM) * 4 + mi][(QN) * 2 + nj] =                             \
                  __builtin_amdgcn_mfma_f32_16x16x32_f16(                     \
                      AF[mi][ks], BF[nj][ks],                                 \
                      acc[(QM) * 4 + mi][(QN) * 2 + nj], 0, 0, 0);            \
  __builtin_amdgcn_s_setprio(0);

  // group read / quadrant MFMA shorthands
#define RD_A0(B) LDA_Q(af0, 0, B)
#define RD_A1(B) LDA_Q(af1, 1, B)
#define RD_B0(B) LDB_Q(bf0, 0, B)
#define RD_B1(B) LDB_Q(bf1, 1, B)
#define M00 MMA_Q(af0, bf0, 0, 0)
#define M01 MMA_Q(af0, bf1, 0, 1)
#define M11 MMA_Q(af1, bf1, 1, 1)
#define M10 MMA_Q(af1, bf0, 1, 0)

  // TILE(T, BIDX, P1RD, P1M, P2RD, P2M, P3RD, P3M, P4M, P4RD)
  // P1RD/P2RD read cur (cA/cB), P3RD/P4RD read nxt (nA/nB).
#define TILE(T, BIDX, P1RD, P1M, P2RD, P2M, P3RD, P3M, P4M, P4RD)             \
  {                                                                           \
    const char *cA = (const char *)&As[BIDX][0];                              \
    const char *cB = (const char *)&Bs[BIDX][0];                              \
    const char *nA = (const char *)&As[(BIDX) ^ 1][0];                        \
    const char *nB = (const char *)&Bs[(BIDX) ^ 1][0];                        \
    (void)cA; (void)cB; (void)nA; (void)nB;                                   \
    const bool s1 = (T) + 1 < NT;                                             \
    const bool s2 = (T) + 2 < NT;                                             \
    P1RD;                                                                     \
    FENCE();                                                                  \
    P1M;                                                                      \
    P2RD;                                                                     \
    FENCE();                                                                  \
    P2M;                                                                      \
    VMW0(); /* retires stage loads issued at (T-1)-P4: ~3 phases old */       \
    BAR();  /* mid barrier: cur-buf reads done -> buf reusable at P4 */       \
    if (s1) { P3RD; }                                                         \
    FENCE();                                                                  \
    P3M;                                                                      \
    if (s2) {                                                                 \
      STAGE2_A((T) + 2, BIDX, 0); STAGE2_A((T) + 2, BIDX, 2);                 \
      STAGE2_B((T) + 2, BIDX, 0); STAGE2_B((T) + 2, BIDX, 2);                 \
    }                                                                         \
    FENCE();                                                                  \
    P4M;                                                                      \
    if (s1) { P4RD; }                                                         \
    BAR();  /* end barrier */                                                 \
  }

  // prologue: stage X(0), X(1); retire X(0); preload tile-0 entry regs
  // (B0 = tile-0 spanner, A0 = tile-0 first A-half).
  STAGE2_A(0, 0, 0); STAGE2_A(0, 0, 2);
  STAGE2_B(0, 0, 0); STAGE2_B(0, 0, 2);
  STAGE2_A(1, 1, 0); STAGE2_A(1, 1, 2);
  STAGE2_B(1, 1, 0); STAGE2_B(1, 1, 2);
  VMW8();
  BAR();
  RD_B0((const char *)&Bs[0][0]);
  RD_A0((const char *)&As[0][0]);

  // rotation tables (r = t&3):
  //  r | P1 rd   P1 M | P2 rd   P2 M | P3 rd(n) P3 M | P4 M  P4 rd(n)
  //  0 | B1.c    Q00  | A1.c    Q01  | A0       Q11  | Q10   B1
  //  1 | A1.c    Q01  | B0.c    Q11  | B1       Q10  | Q00   A1
  //  2 | B0.c    Q11  | A0.c    Q10  | A1       Q00  | Q01   B0
  //  3 | A0.c    Q10  | B1.c    Q00  | B0       Q01  | Q11   A0
  for (int tt = 0; tt < NT; tt += 4) {
    TILE(tt + 0, 0, RD_B1(cB), M00, RD_A1(cA), M01, RD_A0(nA), M11, M10,
         RD_B1(nB));
    TILE(tt + 1, 1, RD_A1(cA), M01, RD_B0(cB), M11, RD_B1(nB), M10, M00,
         RD_A1(nA));
    TILE(tt + 2, 0, RD_B0(cB), M11, RD_A0(cA), M10, RD_A1(nA), M00, M01,
         RD_B0(nB));
    TILE(tt + 3, 1, RD_A0(cA), M10, RD_B1(cB), M00, RD_B0(nB), M01, M11,
         RD_A0(nA));
  }

#undef TILE
#undef RD_A0
#undef RD_A1
#undef RD_B0
#undef RD_B1
#undef M00
#undef M01
#undef M11
#undef M10
#undef STAGE2_A
#undef STAGE2_B
#undef LDA_Q
#undef LDB_Q
#undef MMA_Q

  // C/D layout: col = lane&15, row = (lane>>4)*4 + reg
  const int fr = l & 15, fq = l >> 4;
  float *Cb = C + (size_t)(by * BM + wm * 128) * NDIM + bx * BN + wn * 64;
#pragma unroll
  for (int i = 0; i < 8; ++i)
#pragma unroll
    for (int j = 0; j < 4; ++j)
#pragma unroll
      for (int r = 0; r < 4; ++r)
        Cb[(size_t)(i * 16 + fq * 4 + r) * NDIM + j * 16 + fr] = acc[i][j][r];
}

// ---------------- fallback: fused dequant GEMM (no workspace needed) -------
__global__ __launch_bounds__(256) void gemm_fused(const float *__restrict__ A,
                                                  const int *__restrict__ W,
                                                  const float *__restrict__ S,
                                                  float *__restrict__ C) {
  __shared__ _Float16 Asf[128 * 64];
  __shared__ _Float16 Bsf[128 * 64];
  const int tid = threadIdx.x;
  const int lane = tid & 63;
  const int wv = tid >> 6;
  const int wm = wv >> 1, wn = wv & 1;
  const int bx = blockIdx.x, by = blockIdx.y;
  const int srow = tid >> 1;
  const int skof = (tid & 1) * 32;

  const float *Ab = A + (size_t)(by * 128 + srow) * KDIM + skof;
  const int *Wb = W + (size_t)(bx * 128 + srow) * KDIM + skof;
  const float *Sb = S + (size_t)(bx * 128 + srow) * NGROUPS;

  f32x4 acc[4][4] = {};
  float4 ar[8];
  int4 wr[8];
  float sc;

#pragma unroll
  for (int u = 0; u < 8; ++u) {
    ar[u] = *(const float4 *)(Ab + u * 4);
    wr[u] = *(const int4 *)(Wb + u * 4);
  }
  sc = Sb[0];

  const int fr = lane & 15;
  const int fq = lane >> 4;
  const int kbase = fq * 8;

  for (int kt = 0; kt < KDIM / 64; ++kt) {
    __syncthreads();
    _Float16 *Ad = &Asf[srow * 64 + skof];
    _Float16 *Bd = &Bsf[srow * 64 + skof];
#pragma unroll
    for (int u = 0; u < 4; ++u) {
      const float4 a0 = ar[2 * u], a1 = ar[2 * u + 1];
      const int4 b0 = wr[2 * u], b1 = wr[2 * u + 1];
      f16x8 ha, hb;
      ha[0] = (_Float16)a0.x; ha[1] = (_Float16)a0.y;
      ha[2] = (_Float16)a0.z; ha[3] = (_Float16)a0.w;
      ha[4] = (_Float16)a1.x; ha[5] = (_Float16)a1.y;
      ha[6] = (_Float16)a1.z; ha[7] = (_Float16)a1.w;
      hb[0] = (_Float16)((float)b0.x * sc); hb[1] = (_Float16)((float)b0.y * sc);
      hb[2] = (_Float16)((float)b0.z * sc); hb[3] = (_Float16)((float)b0.w * sc);
      hb[4] = (_Float16)((float)b1.x * sc); hb[5] = (_Float16)((float)b1.y * sc);
      hb[6] = (_Float16)((float)b1.z * sc); hb[7] = (_Float16)((float)b1.w * sc);
      *(f16x8 *)(Ad + u * 8) = ha;
      *(f16x8 *)(Bd + u * 8) = hb;
    }
    if (kt + 1 < KDIM / 64) {
      const float *An = Ab + (kt + 1) * 64;
      const int *Wn = Wb + (kt + 1) * 64;
#pragma unroll
      for (int u = 0; u < 8; ++u) {
        ar[u] = *(const float4 *)(An + u * 4);
        wr[u] = *(const int4 *)(Wn + u * 4);
      }
      sc = Sb[(kt + 1) >> 1];
    }
    __syncthreads();
#pragma unroll
    for (int ks = 0; ks < 2; ++ks) {
      f16x8 afv[4], bfv[4];
      const int kof = ks * 32 + kbase;
#pragma unroll
      for (int i = 0; i < 4; ++i) {
        afv[i] = *(const f16x8 *)&Asf[(wm * 64 + i * 16 + fr) * 64 + kof];
        bfv[i] = *(const f16x8 *)&Bsf[(wn * 64 + i * 16 + fr) * 64 + kof];
      }
#pragma unroll
      for (int i = 0; i < 4; ++i)
#pragma unroll
        for (int j = 0; j < 4; ++j)
          acc[i][j] = __builtin_amdgcn_mfma_f32_16x16x32_f16(afv[i], bfv[j],
                                                             acc[i][j], 0, 0, 0);
    }
  }

  float *Cb = C + (size_t)(by * 128 + wm * 64) * NDIM + bx * 128 + wn * 64;
#pragma unroll
  for (int i = 0; i < 4; ++i)
#pragma unroll
    for (int j = 0; j < 4; ++j)
#pragma unroll
      for (int r = 0; r < 4; ++r)
        Cb[(size_t)(i * 16 + fq * 4 + r) * NDIM + j * 16 + fr] = acc[i][j][r];
}

extern "C" void kernel_launch(void *const *d_in, const int *in_sizes, int n_in,
                              void *d_out, int out_size, void *d_ws,
                              size_t ws_size, hipStream_t stream) {
  (void)in_sizes; (void)n_in; (void)out_size;
  const float *A = (const float *)d_in[0];
  const int *W = (const int *)d_in[1];
  const float *S = (const float *)d_in[2];
  float *C = (float *)d_out;

  const size_t needA = (size_t)MDIM * KDIM * sizeof(_Float16);
  const size_t needW = (size_t)NDIM * KDIM * sizeof(_Float16);

  if (ws_size >= needA + needW) {
    _Float16 *Ahp = (_Float16 *)d_ws;
    _Float16 *Whp = (_Float16 *)((char *)d_ws + needA);
    cvt_a_kernel<<<2048, 256, 0, stream>>>(A, Ahp);
    cvt_w_kernel<<<2048, 256, 0, stream>>>(W, S, Whp);
    gemm_8phase<<<(MDIM / BM) * (NDIM / BN), 512, 0, stream>>>(Ahp, Whp, C);
  } else {
    dim3 grid(NDIM / 128, MDIM / 128);
    gemm_fused<<<grid, 256, 0, stream>>>(A, W, S, C);
  }
}

// Round 6
// 409.100 us; speedup vs baseline: 1.9449x; 1.9449x over previous
//
#include <hip/hip_runtime.h>

#define MDIM 4096
#define KDIM 4096
#define NDIM 11008
#define NGROUPS 32

#define BM 256
#define BN 256
#define BK 64
#define NT (KDIM / BK)   // 64 K-tiles
#define KB (KDIM * 2)    // row stride in bytes (8192)

typedef _Float16 f16x8 __attribute__((ext_vector_type(8)));
typedef float f32x4 __attribute__((ext_vector_type(4)));

typedef const unsigned int __attribute__((address_space(1))) *gas_t;
typedef unsigned int __attribute__((address_space(3))) *las_t;

__device__ __forceinline__ void gld_lds16(const void *g, void *l) {
  __builtin_amdgcn_global_load_lds((gas_t)g, (las_t)l, 16, 0, 0);
}

// Raw barrier with memory clobber (no implicit vm/lgkm drain).
#define BAR() asm volatile("s_barrier" ::: "memory")
#define VMW4() asm volatile("s_waitcnt vmcnt(4)" ::: "memory")
#define VMW0() asm volatile("s_waitcnt vmcnt(0)" ::: "memory")
// Pin {stages, reads} before the MFMA cluster of a phase.
#define FENCE() __builtin_amdgcn_sched_barrier(0)

// ---------------- prepass: A fp32 -> f16 ----------------
__global__ __launch_bounds__(256) void cvt_a_kernel(const float *__restrict__ a,
                                                    _Float16 *__restrict__ o) {
  const int n8 = (MDIM * KDIM) / 8;
  for (int i = blockIdx.x * blockDim.x + threadIdx.x; i < n8;
       i += gridDim.x * blockDim.x) {
    const float4 v0 = *(const float4 *)(a + (size_t)i * 8);
    const float4 v1 = *(const float4 *)(a + (size_t)i * 8 + 4);
    f16x8 h;
    h[0] = (_Float16)v0.x; h[1] = (_Float16)v0.y;
    h[2] = (_Float16)v0.z; h[3] = (_Float16)v0.w;
    h[4] = (_Float16)v1.x; h[5] = (_Float16)v1.y;
    h[6] = (_Float16)v1.z; h[7] = (_Float16)v1.w;
    *(f16x8 *)(o + (size_t)i * 8) = h;
  }
}

// ---------------- prepass: W int32 -> f16 * scale ----------------
__global__ __launch_bounds__(256) void cvt_w_kernel(const int *__restrict__ w,
                                                    const float *__restrict__ s,
                                                    _Float16 *__restrict__ o) {
  const int n8 = (NDIM * KDIM) / 8;
  for (int i = blockIdx.x * blockDim.x + threadIdx.x; i < n8;
       i += gridDim.x * blockDim.x) {
    const size_t base = (size_t)i * 8;
    const int row = (int)(base >> 12);             // /KDIM
    const int g = ((int)(base & (KDIM - 1))) >> 7; // /GROUPSIZE
    const float sc = s[row * NGROUPS + g];
    const int4 w0 = *(const int4 *)(w + base);
    const int4 w1 = *(const int4 *)(w + base + 4);
    f16x8 h;
    h[0] = (_Float16)((float)w0.x * sc); h[1] = (_Float16)((float)w0.y * sc);
    h[2] = (_Float16)((float)w0.z * sc); h[3] = (_Float16)((float)w0.w * sc);
    h[4] = (_Float16)((float)w1.x * sc); h[5] = (_Float16)((float)w1.y * sc);
    h[6] = (_Float16)((float)w1.z * sc); h[7] = (_Float16)((float)w1.w * sc);
    *(f16x8 *)(o + base) = h;
  }
}

// ---------------- main GEMM: 256x256 tile, BK=64, 8 waves ------------------
// R0 champion schedule (413us) with ONE structural change: B is TRIPLE
// buffered (A dbuf 64KB + B tribuf 96KB = 160KB LDS, full CU capacity), which
// removes the mid-tile barrier entirely -> ONE barrier per K-tile.
// Safety ledger (slot s = t%3 holds B(t)):
//  * stage B(t+2) at tile-t start into slot (t+2)%3 = (t-1)%3. All reads of
//    B(t-1) (tail of t-2: bf0; P1 of t-1: bf1) are lgkm-retired before the
//    end-of-(t-1) barrier -> safe.
//  * stage A(t+1) at tile-t start into As[(t+1)&1] (holds A(t-1); reads all
//    retired before end-of-(t-1) barrier).
//  * vmcnt(4) before the end barrier: in-flight oldest-first is
//    [B(t+1)x4, A(t+1)x4, B(t+2)x4] -> retires B(t+1),A(t+1) (exactly what
//    the post-barrier tail reads need), keeps B(t+2) in flight. Stage loads
//    thus retire a FULL TILE after issue - never blocking (the R5 failure
//    mode inverted).
// Read/MFMA order, FENCE/setprio, swizzle, epilogue: identical to R0.
// LDS XOR-swizzle (16B involution): phys_koff = koff ^ ((row&7)*16), applied
// to the pre-swizzled staging source AND the ds_read address.
__global__ __launch_bounds__(512, 2) void gemm_8phase(
    const _Float16 *__restrict__ Ah, const _Float16 *__restrict__ Wh,
    float *__restrict__ C) {
  // [0,64KB): A slots 0,1 (32KB each); [64KB,160KB): B slots 0,1,2.
  __shared__ __align__(16) char Sh[163840];

  const int tid = threadIdx.x;
  const int l = tid & 63;
  const int w = tid >> 6;   // wave 0..7
  const int wm = w >> 2;    // 0..1 (M half)
  const int wn = w & 3;     // 0..3 (N quarter)

  // XCD-aware bijective swizzle: 688 blocks, 86 per XCD.
  const int wg = blockIdx.x;
  const int swz = (wg & 7) * 86 + (wg >> 3);
  const int bx = swz / 16;   // N tile 0..42
  const int by = swz % 16;   // M tile 0..15

  // staging source (pre-swizzled per lane)
  const int srow = l >> 3;
  const int gk = ((l & 7) ^ srow) * 16;
  const char *Ag =
      (const char *)Ah + (size_t)(by * BM + w * 8 + srow) * KB + gk;
  const char *Bg =
      (const char *)Wh + (size_t)(bx * BN + w * 8 + srow) * KB + gk;

  // fragment-read offsets (bytes)
  const int laneRow = (l & 15) * (BK * 2);
  const int kx0 = ((l >> 4) * 16) ^ ((l & 7) * 16);
  const int kx1 = kx0 ^ 64;

  f32x4 acc[8][4] = {};
  f16x8 af0[4][2], af1[4][2], bf0[2][2], bf1[2][2];

  // rotating LDS slot offsets (bytes into Sh)
  unsigned aC = 0, aN = 32768;
  unsigned bC = 65536, bN = 98304, bS = 131072;

#define STAGE2_A(KT, OFF, S0)                                                 \
  {                                                                           \
    const char *ap_ = Ag + (size_t)(KT) * (BK * 2);                           \
    gld_lds16(ap_ + (size_t)(S0) * (64 * KB),                                 \
              (void *)(Sh + (OFF) + (S0) * 8192 + w * 1024));                 \
    gld_lds16(ap_ + (size_t)((S0) + 1) * (64 * KB),                           \
              (void *)(Sh + (OFF) + ((S0) + 1) * 8192 + w * 1024));           \
  }

#define STAGE2_B(KT, OFF, S0)                                                 \
  {                                                                           \
    const char *bp_ = Bg + (size_t)(KT) * (BK * 2);                           \
    gld_lds16(bp_ + (size_t)(S0) * (64 * KB),                                 \
              (void *)(Sh + (OFF) + (S0) * 8192 + w * 1024));                 \
    gld_lds16(bp_ + (size_t)((S0) + 1) * (64 * KB),                           \
              (void *)(Sh + (OFF) + ((S0) + 1) * 8192 + w * 1024));           \
  }

#define LDA_Q(DST, QM, BASE)                                                  \
  {                                                                           \
    const char *ba_ = (BASE) + (wm * 128 + (QM) * 64) * (BK * 2) + laneRow;   \
    _Pragma("unroll") for (int mi = 0; mi < 4; ++mi) {                        \
      DST[mi][0] = *(const f16x8 *)(ba_ + mi * 2048 + kx0);                   \
      DST[mi][1] = *(const f16x8 *)(ba_ + mi * 2048 + kx1);                   \
    }                                                                         \
  }

#define LDB_Q(DST, QN, BASE)                                                  \
  {                                                                           \
    const char *bb_ = (BASE) + (wn * 64 + (QN) * 32) * (BK * 2) + laneRow;    \
    _Pragma("unroll") for (int nj = 0; nj < 2; ++nj) {                        \
      DST[nj][0] = *(const f16x8 *)(bb_ + nj * 2048 + kx0);                   \
      DST[nj][1] = *(const f16x8 *)(bb_ + nj * 2048 + kx1);                   \
    }                                                                         \
  }

#define MMA_Q(AF, BF, QM, QN)                                                 \
  __builtin_amdgcn_s_setprio(1);                                              \
  _Pragma("unroll") for (int ks = 0; ks < 2; ++ks)                            \
      _Pragma("unroll") for (int mi = 0; mi < 4; ++mi)                        \
          _Pragma("unroll") for (int nj = 0; nj < 2; ++nj)                    \
              acc[(QM) * 4 + mi][(QN) * 2 + nj] =                             \
                  __builtin_amdgcn_mfma_f32_16x16x32_f16(                     \
                      AF[mi][ks], BF[nj][ks],                                 \
                      acc[(QM) * 4 + mi][(QN) * 2 + nj], 0, 0, 0);            \
  __builtin_amdgcn_s_setprio(0);

  // prologue: stage A(0)->a0, B(0)->b0, B(1)->b1; retire A0/B0 (vmcnt(4)
  // keeps B(1) in flight); prefetch tile-0 entry fragments.
  STAGE2_A(0, aC, 0); STAGE2_A(0, aC, 2);
  STAGE2_B(0, bC, 0); STAGE2_B(0, bC, 2);
  STAGE2_B(1, bN, 0); STAGE2_B(1, bN, 2);
  VMW4();
  BAR();
  LDA_Q(af0, 0, (const char *)Sh + aC);
  LDB_Q(bf0, 0, (const char *)Sh + bC);

#pragma unroll 2
  for (int t = 0; t < NT; ++t) {
    const bool s1 = (t + 1 < NT);
    const bool s2 = (t + 2 < NT);
    const char *Ac = (const char *)Sh + aC;
    const char *An = (const char *)Sh + aN;
    const char *Bc = (const char *)Sh + bC;
    const char *Bn = (const char *)Sh + bN;

    // tile top: ALL staging issues here (max latency window; slots safe
    // per the ledger above).
    if (s1) { STAGE2_A(t + 1, aN, 0); STAGE2_A(t + 1, aN, 2); }
    if (s2) { STAGE2_B(t + 2, bS, 0); STAGE2_B(t + 2, bS, 2); }

    // P1: prefetch bf1; MFMA Q00 (counted lgkm)
    LDB_Q(bf1, 1, Bc);
    FENCE();
    MMA_Q(af0, bf0, 0, 0);

    // P2: prefetch af1; MFMA Q01 (counted lgkm)
    LDA_Q(af1, 1, Ac);
    FENCE();
    MMA_Q(af0, bf1, 0, 1);

    // P3/P4: regs-only quadrants
    MMA_Q(af1, bf1, 1, 1);
    MMA_Q(af1, bf0, 1, 0);

    // counted vm retire (loads issued a full tile ago); single barrier
    if (s2) { VMW4(); } else { VMW0(); }
    BAR();  // publish As[(t+1)&1]=A(t+1), Bslot[(t+1)%3]=B(t+1)
    if (s1) {  // next tile's P1 fragments
      LDA_Q(af0, 0, An);
      LDB_Q(bf0, 0, Bn);
    }

    // rotate slots
    { const unsigned ta = aC; aC = aN; aN = ta; }
    { const unsigned tb = bC; bC = bN; bN = bS; bS = tb; }
  }

#undef STAGE2_A
#undef STAGE2_B
#undef LDA_Q
#undef LDB_Q
#undef MMA_Q

  // C/D layout: col = lane&15, row = (lane>>4)*4 + reg
  const int fr = l & 15, fq = l >> 4;
  float *Cb = C + (size_t)(by * BM + wm * 128) * NDIM + bx * BN + wn * 64;
#pragma unroll
  for (int i = 0; i < 8; ++i)
#pragma unroll
    for (int j = 0; j < 4; ++j)
#pragma unroll
      for (int r = 0; r < 4; ++r)
        Cb[(size_t)(i * 16 + fq * 4 + r) * NDIM + j * 16 + fr] = acc[i][j][r];
}

// ---------------- fallback: fused dequant GEMM (no workspace needed) -------
__global__ __launch_bounds__(256) void gemm_fused(const float *__restrict__ A,
                                                  const int *__restrict__ W,
                                                  const float *__restrict__ S,
                                                  float *__restrict__ C) {
  __shared__ _Float16 Asf[128 * 64];
  __shared__ _Float16 Bsf[128 * 64];
  const int tid = threadIdx.x;
  const int lane = tid & 63;
  const int wv = tid >> 6;
  const int wm = wv >> 1, wn = wv & 1;
  const int bx = blockIdx.x, by = blockIdx.y;
  const int srow = tid >> 1;
  const int skof = (tid & 1) * 32;

  const float *Ab = A + (size_t)(by * 128 + srow) * KDIM + skof;
  const int *Wb = W + (size_t)(bx * 128 + srow) * KDIM + skof;
  const float *Sb = S + (size_t)(bx * 128 + srow) * NGROUPS;

  f32x4 acc[4][4] = {};
  float4 ar[8];
  int4 wr[8];
  float sc;

#pragma unroll
  for (int u = 0; u < 8; ++u) {
    ar[u] = *(const float4 *)(Ab + u * 4);
    wr[u] = *(const int4 *)(Wb + u * 4);
  }
  sc = Sb[0];

  const int fr = lane & 15;
  const int fq = lane >> 4;
  const int kbase = fq * 8;

  for (int kt = 0; kt < KDIM / 64; ++kt) {
    __syncthreads();
    _Float16 *Ad = &Asf[srow * 64 + skof];
    _Float16 *Bd = &Bsf[srow * 64 + skof];
#pragma unroll
    for (int u = 0; u < 4; ++u) {
      const float4 a0 = ar[2 * u], a1 = ar[2 * u + 1];
      const int4 b0 = wr[2 * u], b1 = wr[2 * u + 1];
      f16x8 ha, hb;
      ha[0] = (_Float16)a0.x; ha[1] = (_Float16)a0.y;
      ha[2] = (_Float16)a0.z; ha[3] = (_Float16)a0.w;
      ha[4] = (_Float16)a1.x; ha[5] = (_Float16)a1.y;
      ha[6] = (_Float16)a1.z; ha[7] = (_Float16)a1.w;
      hb[0] = (_Float16)((float)b0.x * sc); hb[1] = (_Float16)((float)b0.y * sc);
      hb[2] = (_Float16)((float)b0.z * sc); hb[3] = (_Float16)((float)b0.w * sc);
      hb[4] = (_Float16)((float)b1.x * sc); hb[5] = (_Float16)((float)b1.y * sc);
      hb[6] = (_Float16)((float)b1.z * sc); hb[7] = (_Float16)((float)b1.w * sc);
      *(f16x8 *)(Ad + u * 8) = ha;
      *(f16x8 *)(Bd + u * 8) = hb;
    }
    if (kt + 1 < KDIM / 64) {
      const float *An = Ab + (kt + 1) * 64;
      const int *Wn = Wb + (kt + 1) * 64;
#pragma unroll
      for (int u = 0; u < 8; ++u) {
        ar[u] = *(const float4 *)(An + u * 4);
        wr[u] = *(const int4 *)(Wn + u * 4);
      }
      sc = Sb[(kt + 1) >> 1];
    }
    __syncthreads();
#pragma unroll
    for (int ks = 0; ks < 2; ++ks) {
      f16x8 afv[4], bfv[4];
      const int kof = ks * 32 + kbase;
#pragma unroll
      for (int i = 0; i < 4; ++i) {
        afv[i] = *(const f16x8 *)&Asf[(wm * 64 + i * 16 + fr) * 64 + kof];
        bfv[i] = *(const f16x8 *)&Bsf[(wn * 64 + i * 16 + fr) * 64 + kof];
      }
#pragma unroll
      for (int i = 0; i < 4; ++i)
#pragma unroll
        for (int j = 0; j < 4; ++j)
          acc[i][j] = __builtin_amdgcn_mfma_f32_16x16x32_f16(afv[i], bfv[j],
                                                             acc[i][j], 0, 0, 0);
    }
  }

  float *Cb = C + (size_t)(by * 128 + wm * 64) * NDIM + bx * 128 + wn * 64;
#pragma unroll
  for (int i = 0; i < 4; ++i)
#pragma unroll
    for (int j = 0; j < 4; ++j)
#pragma unroll
      for (int r = 0; r < 4; ++r)
        Cb[(size_t)(i * 16 + fq * 4 + r) * NDIM + j * 16 + fr] = acc[i][j][r];
}

extern "C" void kernel_launch(void *const *d_in, const int *in_sizes, int n_in,
                              void *d_out, int out_size, void *d_ws,
                              size_t ws_size, hipStream_t stream) {
  (void)in_sizes; (void)n_in; (void)out_size;
  const float *A = (const float *)d_in[0];
  const int *W = (const int *)d_in[1];
  const float *S = (const float *)d_in[2];
  float *C = (float *)d_out;

  const size_t needA = (size_t)MDIM * KDIM * sizeof(_Float16);
  const size_t needW = (size_t)NDIM * KDIM * sizeof(_Float16);

  if (ws_size >= needA + needW) {
    _Float16 *Ahp = (_Float16 *)d_ws;
    _Float16 *Whp = (_Float16 *)((char *)d_ws + needA);
    cvt_a_kernel<<<2048, 256, 0, stream>>>(A, Ahp);
    cvt_w_kernel<<<2048, 256, 0, stream>>>(W, S, Whp);
    gemm_8phase<<<(MDIM / BM) * (NDIM / BN), 512, 0, stream>>>(Ahp, Whp, C);
  } else {
    dim3 grid(NDIM / 128, MDIM / 128);
    gemm_fused<<<grid, 256, 0, stream>>>(A, W, S, C);
  }
}

// Round 7
// 398.163 us; speedup vs baseline: 1.9983x; 1.0275x over previous
//
#include <hip/hip_runtime.h>

#define MDIM 4096
#define KDIM 4096
#define NDIM 11008
#define NGROUPS 32

#define BM 256
#define BN 256
#define BK 64
#define NT (KDIM / BK)   // 64 K-tiles
#define KB (KDIM * 2)    // row stride in bytes (8192)

typedef _Float16 f16x8 __attribute__((ext_vector_type(8)));
typedef float f32x4 __attribute__((ext_vector_type(4)));

typedef const unsigned int __attribute__((address_space(1))) *gas_t;
typedef unsigned int __attribute__((address_space(3))) *las_t;

__device__ __forceinline__ void gld_lds16(const void *g, void *l) {
  __builtin_amdgcn_global_load_lds((gas_t)g, (las_t)l, 16, 0, 0);
}

// Raw barrier with memory clobber (no implicit vm/lgkm drain).
#define BAR() asm volatile("s_barrier" ::: "memory")
#define VMW4() asm volatile("s_waitcnt vmcnt(4)" ::: "memory")
#define VMW0() asm volatile("s_waitcnt vmcnt(0)" ::: "memory")
#define FENCE() __builtin_amdgcn_sched_barrier(0)

// ---------------- prepass: A fp32 -> f16 ----------------
__global__ __launch_bounds__(256) void cvt_a_kernel(const float *__restrict__ a,
                                                    _Float16 *__restrict__ o) {
  const int n8 = (MDIM * KDIM) / 8;
  for (int i = blockIdx.x * blockDim.x + threadIdx.x; i < n8;
       i += gridDim.x * blockDim.x) {
    const float4 v0 = *(const float4 *)(a + (size_t)i * 8);
    const float4 v1 = *(const float4 *)(a + (size_t)i * 8 + 4);
    f16x8 h;
    h[0] = (_Float16)v0.x; h[1] = (_Float16)v0.y;
    h[2] = (_Float16)v0.z; h[3] = (_Float16)v0.w;
    h[4] = (_Float16)v1.x; h[5] = (_Float16)v1.y;
    h[6] = (_Float16)v1.z; h[7] = (_Float16)v1.w;
    *(f16x8 *)(o + (size_t)i * 8) = h;
  }
}

// ---------------- prepass: W int32 -> f16 * scale ----------------
__global__ __launch_bounds__(256) void cvt_w_kernel(const int *__restrict__ w,
                                                    const float *__restrict__ s,
                                                    _Float16 *__restrict__ o) {
  const int n8 = (NDIM * KDIM) / 8;
  for (int i = blockIdx.x * blockDim.x + threadIdx.x; i < n8;
       i += gridDim.x * blockDim.x) {
    const size_t base = (size_t)i * 8;
    const int row = (int)(base >> 12);             // /KDIM
    const int g = ((int)(base & (KDIM - 1))) >> 7; // /GROUPSIZE
    const float sc = s[row * NGROUPS + g];
    const int4 w0 = *(const int4 *)(w + base);
    const int4 w1 = *(const int4 *)(w + base + 4);
    f16x8 h;
    h[0] = (_Float16)((float)w0.x * sc); h[1] = (_Float16)((float)w0.y * sc);
    h[2] = (_Float16)((float)w0.z * sc); h[3] = (_Float16)((float)w0.w * sc);
    h[4] = (_Float16)((float)w1.x * sc); h[5] = (_Float16)((float)w1.y * sc);
    h[6] = (_Float16)((float)w1.z * sc); h[7] = (_Float16)((float)w1.w * sc);
    *(f16x8 *)(o + base) = h;
  }
}

// ---------------- main GEMM: 256x256 tile, BK=64, 8 waves ------------------
// R6 champion (triple-buffered B, single barrier/tile, 409us) + fine-grained
// read/MFMA interleave:
//  * each 16-MFMA quadrant is split into 4x MMA4 clusters; the phase's
//    ds_reads are sprinkled between clusters (FENCE-pinned) so the LDS pipe
//    and MFMA pipe run concurrently within each wave, not in alternating
//    bursts.
//  * regs-only Q10 moved AFTER the barrier, interleaved with the 12-read
//    next-tile fragment prefetch (previously the only uncovered burst).
//    Requires B-register parity swap per tile (tail loads next B-QN0 into
//    the register group dead after Q11, while Q10 consumes the other).
// Ledger (unchanged from R6): A dbuf 64KB + B tribuf 96KB = 160KB; stage
// A(t+1)->aN, B(t+2)->bS at tile top; vmcnt(4) before BAR retires
// B(t+1),A(t+1) (issued a full tile earlier - never blocks), keeps B(t+2)
// in flight. Cur-buf reads retire wave-locally before BAR (P2/P3 lgkm
// waits); tail reads touch only published next-buffers.
// LDS XOR-swizzle (16B involution): phys_koff = koff ^ ((row&7)*16), applied
// to the pre-swizzled staging source AND the ds_read address.
__global__ __launch_bounds__(512, 2) void gemm_8phase(
    const _Float16 *__restrict__ Ah, const _Float16 *__restrict__ Wh,
    float *__restrict__ C) {
  // [0,64KB): A slots 0,1 (32KB each); [64KB,160KB): B slots 0,1,2.
  __shared__ __align__(16) char Sh[163840];

  const int tid = threadIdx.x;
  const int l = tid & 63;
  const int w = tid >> 6;   // wave 0..7
  const int wm = w >> 2;    // 0..1 (M half)
  const int wn = w & 3;     // 0..3 (N quarter)

  // XCD-aware bijective swizzle: 688 blocks, 86 per XCD.
  const int wg = blockIdx.x;
  const int swz = (wg & 7) * 86 + (wg >> 3);
  const int bx = swz / 16;   // N tile 0..42
  const int by = swz % 16;   // M tile 0..15

  // staging source (pre-swizzled per lane)
  const int srow = l >> 3;
  const int gk = ((l & 7) ^ srow) * 16;
  const char *Ag =
      (const char *)Ah + (size_t)(by * BM + w * 8 + srow) * KB + gk;
  const char *Bg =
      (const char *)Wh + (size_t)(bx * BN + w * 8 + srow) * KB + gk;

  // fragment-read offsets (bytes)
  const int laneRow = (l & 15) * (BK * 2);
  const int kx0 = ((l >> 4) * 16) ^ ((l & 7) * 16);
  const int kx1 = kx0 ^ 64;

  f32x4 acc[8][4] = {};
  f16x8 af0[4][2], af1[4][2], bfA[2][2], bfB[2][2];

  // rotating LDS slot offsets (bytes into Sh)
  unsigned aC = 0, aN = 32768;
  unsigned bC = 65536, bN = 98304, bS = 131072;

#define STAGE2_A(KT, OFF, S0)                                                 \
  {                                                                           \
    const char *ap_ = Ag + (size_t)(KT) * (BK * 2);                           \
    gld_lds16(ap_ + (size_t)(S0) * (64 * KB),                                 \
              (void *)(Sh + (OFF) + (S0) * 8192 + w * 1024));                 \
    gld_lds16(ap_ + (size_t)((S0) + 1) * (64 * KB),                           \
              (void *)(Sh + (OFF) + ((S0) + 1) * 8192 + w * 1024));           \
  }

#define STAGE2_B(KT, OFF, S0)                                                 \
  {                                                                           \
    const char *bp_ = Bg + (size_t)(KT) * (BK * 2);                           \
    gld_lds16(bp_ + (size_t)(S0) * (64 * KB),                                 \
              (void *)(Sh + (OFF) + (S0) * 8192 + w * 1024));                 \
    gld_lds16(bp_ + (size_t)((S0) + 1) * (64 * KB),                           \
              (void *)(Sh + (OFF) + ((S0) + 1) * 8192 + w * 1024));           \
  }

  // 2-read fragment loads (one mi / one nj, both k-halves)
#define RDA2(DST, MI, QM, BASE)                                               \
  {                                                                           \
    const char *ba_ = (BASE) + (wm * 128 + (QM) * 64) * (BK * 2) + laneRow;   \
    DST[MI][0] = *(const f16x8 *)(ba_ + (MI) * 2048 + kx0);                   \
    DST[MI][1] = *(const f16x8 *)(ba_ + (MI) * 2048 + kx1);                   \
  }

#define RDB2(DST, NJ, QN, BASE)                                               \
  {                                                                           \
    const char *bb_ = (BASE) + (wn * 64 + (QN) * 32) * (BK * 2) + laneRow;    \
    DST[NJ][0] = *(const f16x8 *)(bb_ + (NJ) * 2048 + kx0);                   \
    DST[NJ][1] = *(const f16x8 *)(bb_ + (NJ) * 2048 + kx1);                   \
  }

  // 4-MFMA cluster: quadrant (QM,QN), k-step KS, M-frags MI0..MI0+1
#define MMA4(AF, BF, QM, QN, KS, MI0)                                         \
  __builtin_amdgcn_s_setprio(1);                                              \
  _Pragma("unroll") for (int mi = (MI0); mi < (MI0) + 2; ++mi)                \
      _Pragma("unroll") for (int nj = 0; nj < 2; ++nj)                        \
          acc[(QM) * 4 + mi][(QN) * 2 + nj] =                                 \
              __builtin_amdgcn_mfma_f32_16x16x32_f16(                         \
                  AF[mi][KS], BF[nj][KS],                                     \
                  acc[(QM) * 4 + mi][(QN) * 2 + nj], 0, 0, 0);                \
  __builtin_amdgcn_s_setprio(0);

#define MMA_Q(AF, BF, QM, QN)                                                 \
  MMA4(AF, BF, QM, QN, 0, 0); MMA4(AF, BF, QM, QN, 0, 2);                     \
  MMA4(AF, BF, QM, QN, 1, 0); MMA4(AF, BF, QM, QN, 1, 2);

  // TILE(T, B0, B1): B0 holds this tile's B-QN0 (loaded at previous tile's
  // P4 tail); B1 is scratch: gets B-QN1-cur in P1, then next tile's B-QN0
  // in P4 (dead after Q11 by then).
#define TILE(T, B0, B1)                                                       \
  {                                                                           \
    const bool s1 = (T) + 1 < NT;                                             \
    const bool s2 = (T) + 2 < NT;                                             \
    const char *Ac = (const char *)Sh + aC;                                   \
    const char *An = (const char *)Sh + aN;                                   \
    const char *Bc = (const char *)Sh + bC;                                   \
    const char *Bn = (const char *)Sh + bN;                                   \
    /* tile top: all staging (max latency window; slots safe per ledger) */   \
    if (s1) { STAGE2_A((T) + 1, aN, 0); STAGE2_A((T) + 1, aN, 2); }           \
    if (s2) { STAGE2_B((T) + 2, bS, 0); STAGE2_B((T) + 2, bS, 2); }           \
    /* P1: Q00 on (af0,B0); interleave B-QN1-cur reads into B1 */             \
    RDB2(B1, 0, 1, Bc);                                                       \
    FENCE(); MMA4(af0, B0, 0, 0, 0, 0);                                       \
    RDB2(B1, 1, 1, Bc);                                                       \
    FENCE(); MMA4(af0, B0, 0, 0, 0, 2);                                       \
    FENCE(); MMA4(af0, B0, 0, 0, 1, 0);                                       \
    FENCE(); MMA4(af0, B0, 0, 0, 1, 2);                                       \
    /* P2: Q01 on (af0,B1); interleave A-QM1-cur reads into af1 */            \
    RDA2(af1, 0, 1, Ac); RDA2(af1, 1, 1, Ac);                                 \
    FENCE(); MMA4(af0, B1, 0, 1, 0, 0);                                       \
    RDA2(af1, 2, 1, Ac); RDA2(af1, 3, 1, Ac);                                 \
    FENCE(); MMA4(af0, B1, 0, 1, 0, 2);                                       \
    FENCE(); MMA4(af0, B1, 0, 1, 1, 0);                                       \
    FENCE(); MMA4(af0, B1, 0, 1, 1, 2);                                       \
    /* P3: Q11 on (af1,B1) regs-only */                                       \
    MMA_Q(af1, B1, 1, 1);                                                     \
    /* counted vm retire (loads a full tile old); publish barrier */          \
    if (s2) { VMW4(); } else { VMW0(); }                                      \
    BAR();                                                                    \
    /* P4: Q10 on (af1,B0) shadows the next-tile fragment prefetch */         \
    if (s1) { RDA2(af0, 0, 0, An); RDA2(af0, 1, 0, An); }                     \
    FENCE(); MMA4(af1, B0, 1, 0, 0, 0);                                       \
    if (s1) { RDA2(af0, 2, 0, An); RDA2(af0, 3, 0, An); }                     \
    FENCE(); MMA4(af1, B0, 1, 0, 0, 2);                                       \
    if (s1) { RDB2(B1, 0, 0, Bn); }                                           \
    FENCE(); MMA4(af1, B0, 1, 0, 1, 0);                                       \
    if (s1) { RDB2(B1, 1, 0, Bn); }                                           \
    FENCE(); MMA4(af1, B0, 1, 0, 1, 2);                                       \
    /* rotate LDS slots */                                                    \
    { const unsigned ta = aC; aC = aN; aN = ta; }                             \
    { const unsigned tb = bC; bC = bN; bN = bS; bS = tb; }                    \
  }

  // prologue: stage A(0)->a0, B(0)->b0, B(1)->b1; vmcnt(4) keeps B(1) in
  // flight; preload tile-0 entry fragments (af0 = A-QM0, bfA = B-QN0).
  STAGE2_A(0, aC, 0); STAGE2_A(0, aC, 2);
  STAGE2_B(0, bC, 0); STAGE2_B(0, bC, 2);
  STAGE2_B(1, bN, 0); STAGE2_B(1, bN, 2);
  VMW4();
  BAR();
  {
    const char *A0 = (const char *)Sh + aC;
    const char *B0p = (const char *)Sh + bC;
    RDA2(af0, 0, 0, A0); RDA2(af0, 1, 0, A0);
    RDA2(af0, 2, 0, A0); RDA2(af0, 3, 0, A0);
    RDB2(bfA, 0, 0, B0p); RDB2(bfA, 1, 0, B0p);
  }

  for (int t = 0; t < NT; t += 2) {
    TILE(t, bfA, bfB);
    TILE(t + 1, bfB, bfA);
  }

#undef TILE
#undef STAGE2_A
#undef STAGE2_B
#undef RDA2
#undef RDB2
#undef MMA4
#undef MMA_Q

  // C/D layout: col = lane&15, row = (lane>>4)*4 + reg
  const int fr = l & 15, fq = l >> 4;
  float *Cb = C + (size_t)(by * BM + wm * 128) * NDIM + bx * BN + wn * 64;
#pragma unroll
  for (int i = 0; i < 8; ++i)
#pragma unroll
    for (int j = 0; j < 4; ++j)
#pragma unroll
      for (int r = 0; r < 4; ++r)
        Cb[(size_t)(i * 16 + fq * 4 + r) * NDIM + j * 16 + fr] = acc[i][j][r];
}

// ---------------- fallback: fused dequant GEMM (no workspace needed) -------
__global__ __launch_bounds__(256) void gemm_fused(const float *__restrict__ A,
                                                  const int *__restrict__ W,
                                                  const float *__restrict__ S,
                                                  float *__restrict__ C) {
  __shared__ _Float16 Asf[128 * 64];
  __shared__ _Float16 Bsf[128 * 64];
  const int tid = threadIdx.x;
  const int lane = tid & 63;
  const int wv = tid >> 6;
  const int wm = wv >> 1, wn = wv & 1;
  const int bx = blockIdx.x, by = blockIdx.y;
  const int srow = tid >> 1;
  const int skof = (tid & 1) * 32;

  const float *Ab = A + (size_t)(by * 128 + srow) * KDIM + skof;
  const int *Wb = W + (size_t)(bx * 128 + srow) * KDIM + skof;
  const float *Sb = S + (size_t)(bx * 128 + srow) * NGROUPS;

  f32x4 acc[4][4] = {};
  float4 ar[8];
  int4 wr[8];
  float sc;

#pragma unroll
  for (int u = 0; u < 8; ++u) {
    ar[u] = *(const float4 *)(Ab + u * 4);
    wr[u] = *(const int4 *)(Wb + u * 4);
  }
  sc = Sb[0];

  const int fr = lane & 15;
  const int fq = lane >> 4;
  const int kbase = fq * 8;

  for (int kt = 0; kt < KDIM / 64; ++kt) {
    __syncthreads();
    _Float16 *Ad = &Asf[srow * 64 + skof];
    _Float16 *Bd = &Bsf[srow * 64 + skof];
#pragma unroll
    for (int u = 0; u < 4; ++u) {
      const float4 a0 = ar[2 * u], a1 = ar[2 * u + 1];
      const int4 b0 = wr[2 * u], b1 = wr[2 * u + 1];
      f16x8 ha, hb;
      ha[0] = (_Float16)a0.x; ha[1] = (_Float16)a0.y;
      ha[2] = (_Float16)a0.z; ha[3] = (_Float16)a0.w;
      ha[4] = (_Float16)a1.x; ha[5] = (_Float16)a1.y;
      ha[6] = (_Float16)a1.z; ha[7] = (_Float16)a1.w;
      hb[0] = (_Float16)((float)b0.x * sc); hb[1] = (_Float16)((float)b0.y * sc);
      hb[2] = (_Float16)((float)b0.z * sc); hb[3] = (_Float16)((float)b0.w * sc);
      hb[4] = (_Float16)((float)b1.x * sc); hb[5] = (_Float16)((float)b1.y * sc);
      hb[6] = (_Float16)((float)b1.z * sc); hb[7] = (_Float16)((float)b1.w * sc);
      *(f16x8 *)(Ad + u * 8) = ha;
      *(f16x8 *)(Bd + u * 8) = hb;
    }
    if (kt + 1 < KDIM / 64) {
      const float *An = Ab + (kt + 1) * 64;
      const int *Wn = Wb + (kt + 1) * 64;
#pragma unroll
      for (int u = 0; u < 8; ++u) {
        ar[u] = *(const float4 *)(An + u * 4);
        wr[u] = *(const int4 *)(Wn + u * 4);
      }
      sc = Sb[(kt + 1) >> 1];
    }
    __syncthreads();
#pragma unroll
    for (int ks = 0; ks < 2; ++ks) {
      f16x8 afv[4], bfv[4];
      const int kof = ks * 32 + kbase;
#pragma unroll
      for (int i = 0; i < 4; ++i) {
        afv[i] = *(const f16x8 *)&Asf[(wm * 64 + i * 16 + fr) * 64 + kof];
        bfv[i] = *(const f16x8 *)&Bsf[(wn * 64 + i * 16 + fr) * 64 + kof];
      }
#pragma unroll
      for (int i = 0; i < 4; ++i)
#pragma unroll
        for (int j = 0; j < 4; ++j)
          acc[i][j] = __builtin_amdgcn_mfma_f32_16x16x32_f16(afv[i], bfv[j],
                                                             acc[i][j], 0, 0, 0);
    }
  }

  float *Cb = C + (size_t)(by * 128 + wm * 64) * NDIM + bx * 128 + wn * 64;
#pragma unroll
  for (int i = 0; i < 4; ++i)
#pragma unroll
    for (int j = 0; j < 4; ++j)
#pragma unroll
      for (int r = 0; r < 4; ++r)
        Cb[(size_t)(i * 16 + fq * 4 + r) * NDIM + j * 16 + fr] = acc[i][j][r];
}

extern "C" void kernel_launch(void *const *d_in, const int *in_sizes, int n_in,
                              void *d_out, int out_size, void *d_ws,
                              size_t ws_size, hipStream_t stream) {
  (void)in_sizes; (void)n_in; (void)out_size;
  const float *A = (const float *)d_in[0];
  const int *W = (const int *)d_in[1];
  const float *S = (const float *)d_in[2];
  float *C = (float *)d_out;

  const size_t needA = (size_t)MDIM * KDIM * sizeof(_Float16);
  const size_t needW = (size_t)NDIM * KDIM * sizeof(_Float16);

  if (ws_size >= needA + needW) {
    _Float16 *Ahp = (_Float16 *)d_ws;
    _Float16 *Whp = (_Float16 *)((char *)d_ws + needA);
    cvt_a_kernel<<<2048, 256, 0, stream>>>(A, Ahp);
    cvt_w_kernel<<<2048, 256, 0, stream>>>(W, S, Whp);
    gemm_8phase<<<(MDIM / BM) * (NDIM / BN), 512, 0, stream>>>(Ahp, Whp, C);
  } else {
    dim3 grid(NDIM / 128, MDIM / 128);
    gemm_fused<<<grid, 256, 0, stream>>>(A, W, S, C);
  }
}